// Round 17
// baseline (563.214 us; speedup 1.0000x reference)
//
#include <hip/hip_runtime.h>
#include <math.h>

#define NDIS 8192
#define NMIR 16384
#define NTOT 24576
#define DIMD 256
#define BPAIR 65536
#define KSEL 50
#define EPSF 1e-8f
#define CBC 32     // columns per LDS chunk
#define CAP 80     // per-strip candidate cap (disease lam~40, mirna lam~32)
#define PSTR 320   // part stride per row (u32 keys) = 4*80
#define ZD 2.066f  // E[count] ~ 160 total for disease
#define ZM 2.418f  // E[count] ~ 128 total for mirna
#define ZFD 0.9035f  // fallback z (E ~ 1500)
#define ZFM 1.331f
#define NKB 768    // knn blocks (512 mirna SW=4096 + 256 disease SW=2048)

typedef __attribute__((ext_vector_type(8))) short bf16x8;
typedef __attribute__((ext_vector_type(4))) float f32x4;
typedef unsigned long long ull;

__device__ __forceinline__ float wredsum(float v) {
#pragma unroll
  for (int off = 1; off < 64; off <<= 1) v += __shfl_xor(v, off, 64);
  return v;
}

__device__ __forceinline__ int wredsumi(int v) {
#pragma unroll
  for (int off = 1; off < 64; off <<= 1) v += __shfl_xor(v, off, 64);
  return v;
}

__device__ __forceinline__ float softplusf(float x) {
  return fmaxf(x, 0.0f) + log1pf(expf(-fabsf(x)));
}

__device__ __forceinline__ float dot4f(const float4 a, const float4 b) {
  return a.x * b.x + a.y * b.y + a.z * b.z + a.w * b.w;
}

__device__ __forceinline__ unsigned short f2bf(float f) {
  unsigned u = __float_as_uint(f);
  unsigned r = (u + 0x7fffu + ((u >> 16) & 1u)) >> 16;
  return (unsigned short)r;
}

__device__ __forceinline__ float b2f(unsigned short x) {
  return __uint_as_float((unsigned)x << 16);
}

// monotone float -> ordered-uint
__device__ __forceinline__ unsigned ordu(float f) {
  unsigned u = __float_as_uint(f);
  return (u & 0x80000000u) ? ~u : (u | 0x80000000u);
}

// ---------- Kernel 0: fused fp32->bf16 convert + 32-row-slice col sums ----
// 768 blocks x 32 rows (3072 waves). Sums accumulate bf16-ROUNDED values so
// tau matches the sims the MFMA actually computes.
__global__ __launch_bounds__(256) void convert_colsum_kernel(
    const float* __restrict__ in, unsigned short* __restrict__ out,
    float* __restrict__ colpart) {
  const int d = threadIdx.x;
  const int r0 = blockIdx.x * 32;
  float s = 0.0f;
  for (int i = 0; i < 32; ++i) {
    const float v = in[(size_t)(r0 + i) * DIMD + d];
    const unsigned short b = f2bf(v);
    out[(size_t)(r0 + i) * DIMD + d] = b;
    s += b2f(b);
  }
  colpart[blockIdx.x * DIMD + d] = s;
}

// ---------- Kernel S1b: reduce slice sums -> per-group column means ------
__global__ __launch_bounds__(256) void colmean_kernel(
    const float* __restrict__ colpart, float* __restrict__ colmean) {
  const int g = blockIdx.x;
  const int d = threadIdx.x;
  const int b0 = g ? 256 : 0, b1 = g ? 768 : 256;
  const float Ninv = 1.0f / (g ? (float)NMIR : (float)NDIS);
  float s = 0.0f;
  for (int b = b0; b < b1; ++b) s += colpart[b * DIMD + d];
  colmean[g * DIMD + d] = s * Ninv;
}

// ---------- Kernel S2: per-row tau = mu + z*sigma ----------
__global__ __launch_bounds__(256) void tau_kernel(
    const unsigned short* __restrict__ embb, const float* __restrict__ colmean,
    float* __restrict__ tau, float2* __restrict__ musig,
    unsigned* __restrict__ cnts, unsigned* __restrict__ flags) {
  __shared__ float cm[DIMD];
  const int lane = threadIdx.x & 63;
  const int widx = threadIdx.x >> 6;
  const bool bism = blockIdx.x >= 32;
  cm[threadIdx.x] = colmean[(bism ? DIMD : 0) + threadIdx.x];
  __syncthreads();
  const int r0 = blockIdx.x * 256 + widx * 64;
  const float z = bism ? ZM : ZD;
  for (int rr = 0; rr < 64; ++rr) {
    const int row = r0 + rr;
    const float4 cmv = ((const float4*)cm)[lane];
    const ushort4 u = ((const ushort4*)(embb + (size_t)row * DIMD))[lane];
    const float fx = b2f(u.x), fy = b2f(u.y), fz = b2f(u.z), fw = b2f(u.w);
    float dot = fx * cmv.x + fy * cmv.y + fz * cmv.z + fw * cmv.w;
    float nsq = fx * fx + fy * fy + fz * fz + fw * fw;
    dot = wredsum(dot);
    nsq = wredsum(nsq);
    const float sig = sqrtf(nsq);
    if (lane == 0) {
      tau[row] = dot + z * sig;
      musig[row] = make_float2(dot, sig);
      flags[row] = 0u;
    }
    if (lane < 4) cnts[row * 4 + lane] = 0u;
  }
}

// ---------- Kernel B: MFMA sim-GEMM + tau-gated keys + fused pair tail ----
// Grid 768 = exactly 3 blocks/CU. bid<512: mirna (rt=bid>>2, strip=bid&3,
// SW=4096); else disease (SW=2048). Triple-buffered LDS (3x16KB), raw
// s_barrier + counted vmcnt(4). LDS read addresses via precomputed per-lane
// bases vE/vO (XOR swizzle decomposed: addr = base +- s*64 + kk*64, so all
// kk offsets are compile-time immediates -> ~40 fewer VALU/chunk).
// (256,3) is the register wall: hipcc splits the unified pool ~50/50
// arch/AGPR with MFMA (arch caps 84/64/48/40 measured at 3/4/5/6 waves).
__global__ __launch_bounds__(256, 3) void knn_kernel(
    const unsigned short* __restrict__ embb, const float* __restrict__ tau,
    unsigned* __restrict__ part, unsigned* __restrict__ cnts,
    unsigned* __restrict__ flags, const float* __restrict__ h,
    const float* __restrict__ srci, const float* __restrict__ dsti,
    const int* __restrict__ dis, const int* __restrict__ mir,
    float* __restrict__ scores, float* __restrict__ pairpart) {
  __shared__ char lds[3 * CBC * 512];  // 3 x 16KB B chunks
  __shared__ float wsum[4];

  const int tid = threadIdx.x;
  const int lane = tid & 63;
  const int widx = tid >> 6;
  const int q4 = lane >> 4;
  const int l15 = lane & 15;
  const int sh16 = q4 * 16;
  const unsigned lmask = (1u << l15) - 1u;

  const int bid = blockIdx.x;
  const bool ism = bid < 512;
  const int rt = ism ? (bid >> 2) : ((bid - 512) >> 2);
  const int strip = ism ? (bid & 3) : ((bid - 512) & 3);
  const int sw = ism ? 4096 : 2048;
  const int nch = sw / CBC;
  const int gbase = ism ? NDIS : 0;
  const unsigned short* fb = embb + (size_t)gbase * DIMD;

  const int rowbase = rt * 128 + widx * 32;  // group-local first row of wave
  const int colstart = strip * sw;
  const char* gb = (const char*)fb;

  // A fragments for 2 row groups (16 rows each)
  bf16x8 afr[2][8];
#pragma unroll
  for (int rg = 0; rg < 2; ++rg) {
    const int arow = rowbase + rg * 16 + l15;
    const char* ab = (const char*)fb + (size_t)arow * 512 + q4 * 16;
#pragma unroll
    for (int kk = 0; kk < 8; ++kk)
      afr[rg][kk] = *(const bf16x8*)(ab + (size_t)kk * 64);
  }

  // LDS read bases: swizzle addr = col*512 + ((kk*64 + q4*16) ^ xr) with
  // xr = (l15&7)<<4 decomposes to base +- s*64 + kk*64 (s = bit2 of l15).
  const int s6 = ((l15 >> 2) & 1) * 64;
  const int Lc = (q4 * 16) ^ ((l15 & 3) << 4);
  int vE[2], vO[2];
#pragma unroll
  for (int t = 0; t < 2; ++t) {
    const int base = t * 8192 + l15 * 512 + Lc;
    vE[t] = base + s6;
    vO[t] = base - s6;
  }

  float tau8[2][4];
  unsigned offb[2];
  int cnt8[2][4];
#pragma unroll
  for (int rg = 0; rg < 2; ++rg) {
    const int db = rowbase + rg * 16 + q4 * 4;
    offb[rg] = (unsigned)(gbase + db) * PSTR + strip * CAP;
#pragma unroll
    for (int j = 0; j < 4; ++j) {
      tau8[rg][j] = tau[gbase + db + j];
      cnt8[rg][j] = 0;
    }
  }

  // B chunk staging: linear LDS dest, inverse-swizzled global source
  auto stage = [&](int dstOff, int cb0n) {
#pragma unroll
    for (int it = 0; it < 4; ++it) {
      const int m = widx * 4 + it;
      const int col = m * 2 + (lane >> 5);
      const int qq = (lane & 31) * 16;
      const int koff = qq ^ ((col & 7) << 4);
      const char* src = gb + (size_t)(colstart + cb0n + col) * 512 + koff;
      __builtin_amdgcn_global_load_lds(
          (const __attribute__((address_space(1))) void*)src,
          (__attribute__((address_space(3))) void*)(lds + dstOff + m * 1024),
          16, 0, 0);
    }
  };

  int o0 = 0, o1 = 16384, o2 = 32768;
  stage(o0, 0);
  stage(o1, CBC);
  for (int ch = 0; ch < nch; ++ch) {
    // counted drain: chunk ch's 4 DMAs complete; ch+1's stay in flight.
    if (ch < nch - 1)
      asm volatile("s_waitcnt vmcnt(4)" ::: "memory");
    else
      asm volatile("s_waitcnt vmcnt(0)" ::: "memory");
    __builtin_amdgcn_sched_barrier(0);
    __builtin_amdgcn_s_barrier();
    __builtin_amdgcn_sched_barrier(0);
    if (ch + 2 < nch) stage(o2, (ch + 2) * CBC);

    const int cb0 = ch * CBC;
    f32x4 acc[2][2];
#pragma unroll
    for (int rg = 0; rg < 2; ++rg)
#pragma unroll
      for (int t = 0; t < 2; ++t) acc[rg][t] = (f32x4){0.f, 0.f, 0.f, 0.f};

#pragma unroll
    for (int t = 0; t < 2; ++t) {
      const char* pE = lds + o0 + vE[t];
      const char* pO = lds + o0 + vO[t];
#pragma unroll
      for (int kp = 0; kp < 4; ++kp) {
        const bf16x8 be = *(const bf16x8*)(pE + kp * 128);
        acc[0][t] = __builtin_amdgcn_mfma_f32_16x16x32_bf16(afr[0][2 * kp], be,
                                                            acc[0][t], 0, 0, 0);
        acc[1][t] = __builtin_amdgcn_mfma_f32_16x16x32_bf16(afr[1][2 * kp], be,
                                                            acc[1][t], 0, 0, 0);
        const bf16x8 bo = *(const bf16x8*)(pO + 64 + kp * 128);
        acc[0][t] = __builtin_amdgcn_mfma_f32_16x16x32_bf16(
            afr[0][2 * kp + 1], bo, acc[0][t], 0, 0, 0);
        acc[1][t] = __builtin_amdgcn_mfma_f32_16x16x32_bf16(
            afr[1][2 * kp + 1], bo, acc[1][t], 0, 0, 0);
      }
    }

    // selection (this buffer's next overwrite is 2 barriers away)
#pragma unroll
    for (int t = 0; t < 2; ++t) {
      const int colb = colstart + cb0 + t * 16;
      const unsigned kc = (unsigned)(16383 - (colb + l15));  // rev-idx tiebrk
#pragma unroll
      for (int rg = 0; rg < 2; ++rg) {
        const bool dchr = (colb == rowbase + rg * 16);  // scalar, rare
#pragma unroll
        for (int j = 0; j < 4; ++j) {
          const float v = acc[rg][t][j];
          bool ok = v > tau8[rg][j];
          if (dchr) ok = ok && (l15 != (q4 * 4 + j));  // skip diagonal
          const ull m = __ballot(ok);
          if (m) {  // wave-uniform early-out
            const unsigned m16 = (unsigned)(m >> sh16) & 0xFFFFu;
            const int rank = __popc(m16 & lmask);
            const int slot = cnt8[rg][j] + rank;
            if (ok && slot < CAP)
              part[offb[rg] + (unsigned)(j * PSTR) + slot] =
                  ((ordu(v) >> 14) << 14) | kc;
            cnt8[rg][j] += __popc(m16);
          }
        }
      }
    }

    const int tp = o0; o0 = o1; o1 = o2; o2 = tp;  // rotate buffers
  }

#pragma unroll
  for (int rg = 0; rg < 2; ++rg) {
#pragma unroll
    for (int j = 0; j < 4; ++j) {
      if (l15 == 0) {
        const int growg = gbase + rowbase + rg * 16 + q4 * 4 + j;
        const int c = cnt8[rg][j];
        cnts[growg * 4 + strip] = (unsigned)(c < CAP ? c : CAP);
        if (c > CAP) flags[growg] = 1u;  // overflow -> exact fallback
      }
    }
  }

  // ---- fused pair phase: this block's slice of the contrastive work ----
  const int gw = bid * 4 + widx;  // 3072 waves
  float lsum = 0.0f;
  for (int b = gw; b < BPAIR; b += NKB * 4) {
    const int d = dis[b];
    const int m = mir[b];
    const float4 a4 = ((const float4*)(h + (size_t)d * DIMD))[lane];
    const float4 m4 = ((const float4*)(h + (size_t)m * DIMD))[lane];
    const float4 s4 = ((const float4*)(srci + (size_t)b * DIMD))[lane];
    const float4 t4 = ((const float4*)(dsti + (size_t)b * DIMD))[lane];
    float aa = dot4f(a4, a4);
    float ss = dot4f(s4, s4);
    float tt = dot4f(t4, t4);
    float as = dot4f(a4, s4);
    float at = dot4f(a4, t4);
    float am = dot4f(a4, m4);
    aa = wredsum(aa); ss = wredsum(ss); tt = wredsum(tt);
    as = wredsum(as); at = wredsum(at); am = wredsum(am);
    const float ra = fmaxf(sqrtf(aa), EPSF);
    const float pos = as / (ra * fmaxf(sqrtf(ss), EPSF));
    const float neg = at / (ra * fmaxf(sqrtf(tt), EPSF));
    lsum += softplusf(neg - pos);
    if (lane == 0) scores[b] = 1.0f / (1.0f + expf(-am));
  }
  if (lane == 0) wsum[widx] = lsum;
  __syncthreads();
  if (tid == 0)
    pairpart[bid] = (wsum[0] + wsum[1]) + (wsum[2] + wsum[3]);
}

// ---------- Kernel F: exact fallback for flagged / under-full rows ----------
__global__ __launch_bounds__(256) void fallback_kernel(
    const unsigned short* __restrict__ embb, const float2* __restrict__ musig,
    unsigned* __restrict__ part, unsigned* __restrict__ cnts,
    const unsigned* __restrict__ flags, unsigned* __restrict__ fbbuf) {
  __shared__ unsigned short frow[4][DIMD];
  const int lane = threadIdx.x & 63;
  const int widx = threadIdx.x >> 6;
  const int wid = blockIdx.x * 4 + widx;
  const ull bel = (1ull << lane) - 1ull;

  for (int row = wid * 96; row < wid * 96 + 96; ++row) {
    unsigned tot = 0;
    for (int s = 0; s < 4; ++s) tot += cnts[row * 4 + s];
    if (!(flags[row] || tot < KSEL)) continue;

    const bool ism = row >= NDIS;
    const int lrow = ism ? row - NDIS : row;
    const int Ng = ism ? NMIR : NDIS;
    const unsigned short* fb = embb + (ism ? (size_t)NDIS * DIMD : 0);
    const float2 ms = musig[row];
    const float tp = ms.x + (ism ? ZFM : ZFD) * ms.y;

    ((ushort4*)frow[widx])[lane] =
        ((const ushort4*)(fb + (size_t)lrow * DIMD))[lane];

    unsigned* fk = fbbuf + (size_t)wid * 4096;
    int fc = 0;
    for (int cb = 0; cb < Ng; cb += 64) {
      const int col = cb + lane;
      float s = 0.0f;
      for (int d0 = 0; d0 < DIMD; d0 += 4) {
        const ushort4 uc = *(const ushort4*)(fb + (size_t)col * DIMD + d0);
        const ushort4 ur = *(const ushort4*)(&frow[widx][d0]);
        s += b2f(uc.x) * b2f(ur.x) + b2f(uc.y) * b2f(ur.y) +
             b2f(uc.z) * b2f(ur.z) + b2f(uc.w) * b2f(ur.w);
      }
      const bool a = (s > tp) && (col != lrow);
      const ull m = __ballot(a);
      const int sl = fc + __popcll(m & bel);
      if (a && sl < 4096) fk[sl] = ((ordu(s) >> 14) << 14) | (16383u - col);
      fc += __popcll(m);
    }
    if (fc > 4096) fc = 4096;

    unsigned lo = 0u, hi = 0xFFFFFFFFu;
    for (int it = 0; it < 32; ++it) {
      const unsigned mid = lo + ((hi - lo) >> 1);
      int c = 0;
      for (int i = lane; i < fc; i += 64) c += (fk[i] > mid) ? 1 : 0;
      c = wredsumi(c);
      if (c >= KSEL) lo = mid; else hi = mid;
    }
    int wc = 0;
    for (int base = 0; base < fc; base += 64) {
      const int i = base + lane;
      const bool w = (i < fc) && (fk[i] > lo);
      const ull m = __ballot(w);
      const int pos = wc + __popcll(m & bel);
      if (w) part[(size_t)row * PSTR + pos] = fk[i];
      wc += __popcll(m);
    }
    if (lane < 4) cnts[row * 4 + lane] = (lane == 0) ? KSEL : 0u;
  }
}

// ---------- Kernel B2: merge strips, exact top-50 by key bisect, gather ----
__global__ __launch_bounds__(256) void merge_kernel(
    const unsigned short* __restrict__ embb, const unsigned* __restrict__ part,
    const unsigned* __restrict__ cnts, float* __restrict__ upd_d,
    float* __restrict__ upd_m) {
  __shared__ unsigned kb[4][PSTR];
  const int lane = threadIdx.x & 63;
  const int widx = threadIdx.x >> 6;
  const int row = blockIdx.x * 4 + widx;
  const bool ism = row >= NDIS;
  const int lrow = ism ? row - NDIS : row;
  const unsigned short* fe = embb + (ism ? (size_t)NDIS * DIMD : 0);
  float* upd =
      (ism ? upd_m + (size_t)lrow * DIMD : upd_d + (size_t)lrow * DIMD);
  const ull bel = (1ull << lane) - 1ull;

  int T = 0;
  for (int s = 0; s < 4; ++s) {
    const int c = (int)cnts[row * 4 + s];
    for (int i = lane; i < c; i += 64)
      kb[widx][T + i] = part[(size_t)row * PSTR + s * CAP + i];
    T += c;
  }
  const int nr = (T + 63) >> 6;  // live regs (wave-uniform)
  unsigned k[5];
#pragma unroll
  for (int i = 0; i < 5; ++i) {
    const int idx = i * 64 + lane;
    k[i] = (idx < T) ? kb[widx][idx] : 0u;
  }

  // bisect: largest lo with count(key > lo) >= 50; keys unique -> exact 50
  unsigned lo = 0u, hi = 0xFFFFFFFFu;
  for (int it = 0; it < 32; ++it) {
    const unsigned mid = lo + ((hi - lo) >> 1);
    int c = 0;
#pragma unroll
    for (int i = 0; i < 5; ++i)
      if (i < nr) c += __popcll(__ballot(k[i] > mid));
    if (c >= KSEL) lo = mid; else hi = mid;
  }
  // winners -> column list in LDS
  int wc = 0;
#pragma unroll
  for (int i = 0; i < 5; ++i) {
    if (i < nr) {
      const bool w = k[i] > lo;
      const ull m = __ballot(w);
      const int pos = wc + __popcll(m & bel);
      if (w) kb[widx][pos] = 16383u - (k[i] & 16383u);
      wc += __popcll(m);
    }
  }

  // gather the 50 neighbors (bf16) and average in fp32
  float ax = 0.f, ay = 0.f, az = 0.f, aw = 0.f;
#pragma unroll 10
  for (int t = 0; t < KSEL; ++t) {
    const int col = (int)kb[widx][t];
    const ushort4 u = ((const ushort4*)(fe + (size_t)col * DIMD))[lane];
    ax += b2f(u.x); ay += b2f(u.y); az += b2f(u.z); aw += b2f(u.w);
  }
  const float inv = 1.0f / (float)KSEL;
  float4 o;
  o.x = ax * inv; o.y = ay * inv; o.z = az * inv; o.w = aw * inv;
  ((float4*)upd)[lane] = o;
}

// ---------- Kernel C1: per-128-row partial sums over concatenated upd ----
__global__ __launch_bounds__(256) void center_partial(
    const float* __restrict__ upd, float* __restrict__ part) {
  const int c = threadIdx.x;
  const int r0 = blockIdx.x * 128;
  float s = 0.0f;
  for (int i = 0; i < 128; ++i) s += upd[(size_t)(r0 + i) * DIMD + c];
  part[blockIdx.x * DIMD + c] = s;
}

// ---------- Kernel C2: finalize both centers + norms (grid 2) ----------
__global__ __launch_bounds__(256) void center_final(
    const float* __restrict__ part, float* __restrict__ center,
    float* __restrict__ cnorm) {
  const int g = blockIdx.x;
  const int c = threadIdx.x;
  const int b0 = g ? 64 : 0, b1 = g ? 192 : 64;
  const float N = g ? (float)NMIR : (float)NDIS;
  float s = 0.0f;
  for (int b = b0; b < b1; ++b) s += part[b * DIMD + c];
  s /= N;
  center[g * DIMD + c] = s;
  __shared__ float red[256];
  red[c] = s * s;
  __syncthreads();
  for (int off = 128; off > 0; off >>= 1) {
    if (c < off) red[c] += red[c + off];
    __syncthreads();
  }
  if (c == 0) cnorm[g] = sqrtf(red[0]);
}

// ---------- Kernel D: both groups' cos-vs-centers softplus partials ------
__global__ __launch_bounds__(256) void knn_loss(
    const float* __restrict__ upd_d, const float* __restrict__ upd_m,
    const float* __restrict__ centers, const float* __restrict__ cnorms,
    float* __restrict__ lpa, float* __restrict__ lpb) {
  const int lane = threadIdx.x & 63;
  const int widx = threadIdx.x >> 6;
  const int bid = blockIdx.x;
  const bool ism = bid >= 128;
  const int lb = ism ? bid - 128 : bid;
  const int N = ism ? NMIR : NDIS;
  const int nw = ism ? 1024 : 512;
  const float* upd = ism ? upd_m : upd_d;
  const int gw = lb * 4 + widx;
  const float4 ca = ((const float4*)centers)[lane];
  const float4 cbv = ((const float4*)(centers + DIMD))[lane];
  const float na = fmaxf(cnorms[0], EPSF);
  const float nb = fmaxf(cnorms[1], EPSF);
  float lsum = 0.0f;
  for (int r = gw; r < N; r += nw) {
    const float4 u = ((const float4*)(upd + (size_t)r * DIMD))[lane];
    float uu = dot4f(u, u);
    float uca = dot4f(u, ca);
    float ucb = dot4f(u, cbv);
    uu = wredsum(uu); uca = wredsum(uca); ucb = wredsum(ucb);
    const float nu = fmaxf(sqrtf(uu), EPSF);
    const float sa = uca / (nu * na);
    const float sb = ucb / (nu * nb);
    const float x = ism ? (sa - sb) : (sb - sa);
    lsum += softplusf(x);
  }
  __shared__ float wsum[4];
  if (lane == 0) wsum[widx] = lsum;
  __syncthreads();
  if (threadIdx.x == 0) {
    const float v = (wsum[0] + wsum[1]) + (wsum[2] + wsum[3]);
    if (ism) lpb[lb] = v; else lpa[lb] = v;
  }
}

// ---------- Kernel E: final scalar reductions ----------
__global__ __launch_bounds__(256) void finalize_kernel(
    const float* __restrict__ pairpart, const float* __restrict__ lpa,
    const float* __restrict__ lpb, float* __restrict__ out) {
  __shared__ float red[256];
  const int t = threadIdx.x;

  float s = 0.0f;
  for (int i = t; i < NKB; i += 256) s += pairpart[i];
  red[t] = s;
  __syncthreads();
  for (int off = 128; off > 0; off >>= 1) {
    if (t < off) red[t] += red[t + off];
    __syncthreads();
  }
  const float pairsum = red[0];
  __syncthreads();

  red[t] = (t < 128) ? lpa[t] : 0.0f;
  __syncthreads();
  for (int off = 128; off > 0; off >>= 1) {
    if (t < off) red[t] += red[t + off];
    __syncthreads();
  }
  const float la = red[0];
  __syncthreads();

  red[t] = lpb[t];
  __syncthreads();
  for (int off = 128; off > 0; off >>= 1) {
    if (t < off) red[t] += red[t + off];
    __syncthreads();
  }
  const float lb = red[0];

  if (t == 0) {
    out[BPAIR] = pairsum / (float)BPAIR;
    out[BPAIR + 1] = 0.5f * (la / (float)NDIS + lb / (float)NMIR);
  }
}

extern "C" void kernel_launch(void* const* d_in, const int* in_sizes, int n_in,
                              void* d_out, int out_size, void* d_ws,
                              size_t ws_size, hipStream_t stream) {
  const float* h = (const float*)d_in[0];
  const float* emb = (const float*)d_in[1];
  const float* srci = (const float*)d_in[2];
  const float* dsti = (const float*)d_in[3];
  const int* dis = (const int*)d_in[4];
  const int* mir = (const int*)d_in[5];
  float* out = (float*)d_out;

  float* W = (float*)d_ws;
  float* upd_d = W;                                    // 8192*256 f32
  float* upd_m = upd_d + (size_t)NDIS * DIMD;          // 16384*256 f32
  float* pairpart = upd_m + (size_t)NMIR * DIMD;       // 768 (pad 1024)
  float* cpart = pairpart + 1024;                      // 192*256
  float* centers = cpart + 192 * DIMD;                 // 512
  float* cnorms = centers + 512;                       // 2 (pad 64)
  float* lpa = cnorms + 64;                            // 128
  float* lpb = lpa + 128;                              // 256
  float* colpart = lpb + 256;                          // 768*256
  float* colmean = colpart + 768 * DIMD;               // 512
  float* tau = colmean + 512;                          // 24576
  float2* musig = (float2*)(tau + NTOT);               // 24576 float2
  unsigned* flags = (unsigned*)(musig + NTOT);         // 24576 u32
  unsigned* cnts = flags + NTOT;                       // 24576*4 u32
  unsigned short* embb = (unsigned short*)(cnts + NTOT * 4);  // 24576*256 bf16
  unsigned* part = (unsigned*)(embb + (size_t)NTOT * DIMD);   // 24576*320 u32
  unsigned* fbbuf = part + (size_t)NTOT * PSTR;        // 256*4096 u32

  convert_colsum_kernel<<<768, 256, 0, stream>>>(emb, embb, colpart);
  colmean_kernel<<<2, 256, 0, stream>>>(colpart, colmean);
  tau_kernel<<<96, 256, 0, stream>>>(embb, colmean, tau, musig, cnts, flags);
  knn_kernel<<<NKB, 256, 0, stream>>>(embb, tau, part, cnts, flags, h, srci,
                                      dsti, dis, mir, out, pairpart);
  fallback_kernel<<<64, 256, 0, stream>>>(embb, musig, part, cnts, flags,
                                          fbbuf);
  merge_kernel<<<NTOT / 4, 256, 0, stream>>>(embb, part, cnts, upd_d, upd_m);
  center_partial<<<192, 256, 0, stream>>>(upd_d, cpart);
  center_final<<<2, 256, 0, stream>>>(cpart, centers, cnorms);
  knn_loss<<<384, 256, 0, stream>>>(upd_d, upd_m, centers, cnorms, lpa, lpb);
  finalize_kernel<<<1, 256, 0, stream>>>(pairpart, lpa, lpb, out);
}

// Round 18
// 474.393 us; speedup vs baseline: 1.1872x; 1.1872x over previous
//
#include <hip/hip_runtime.h>
#include <math.h>

#define NDIS 8192
#define NMIR 16384
#define NTOT 24576
#define DIMD 256
#define BPAIR 65536
#define KSEL 50
#define EPSF 1e-8f
#define CBC 32     // columns per LDS chunk
#define CAP 80     // per-strip candidate cap (disease lam~40, mirna lam~32)
#define PSTR 320   // part stride per row (u32 keys) = 4*80
#define ZD 2.066f  // E[count] ~ 160 total for disease
#define ZM 2.418f  // E[count] ~ 128 total for mirna
#define ZFD 0.9035f  // fallback z (E ~ 1500)
#define ZFM 1.331f
#define NKB 768    // knn blocks (512 mirna SW=4096 + 256 disease SW=2048)

typedef __attribute__((ext_vector_type(8))) short bf16x8;
typedef __attribute__((ext_vector_type(4))) float f32x4;
typedef unsigned long long ull;

__device__ __forceinline__ float wredsum(float v) {
#pragma unroll
  for (int off = 1; off < 64; off <<= 1) v += __shfl_xor(v, off, 64);
  return v;
}

__device__ __forceinline__ int wredsumi(int v) {
#pragma unroll
  for (int off = 1; off < 64; off <<= 1) v += __shfl_xor(v, off, 64);
  return v;
}

__device__ __forceinline__ float softplusf(float x) {
  return fmaxf(x, 0.0f) + log1pf(expf(-fabsf(x)));
}

__device__ __forceinline__ float dot4f(const float4 a, const float4 b) {
  return a.x * b.x + a.y * b.y + a.z * b.z + a.w * b.w;
}

__device__ __forceinline__ unsigned short f2bf(float f) {
  unsigned u = __float_as_uint(f);
  unsigned r = (u + 0x7fffu + ((u >> 16) & 1u)) >> 16;
  return (unsigned short)r;
}

__device__ __forceinline__ float b2f(unsigned short x) {
  return __uint_as_float((unsigned)x << 16);
}

// monotone float -> ordered-uint
__device__ __forceinline__ unsigned ordu(float f) {
  unsigned u = __float_as_uint(f);
  return (u & 0x80000000u) ? ~u : (u | 0x80000000u);
}

// ---------- Kernel 0: fp32 -> bf16 conversion of emb (vectorized) ----------
__global__ __launch_bounds__(256) void convert_kernel(
    const float* __restrict__ in, unsigned short* __restrict__ out) {
  const int i = (blockIdx.x * 256 + threadIdx.x) * 4;
  const float4 v = *(const float4*)(in + i);
  ushort4 o;
  o.x = f2bf(v.x); o.y = f2bf(v.y); o.z = f2bf(v.z); o.w = f2bf(v.w);
  *(ushort4*)(out + i) = o;
}

// ---------- Kernel S1: per-256-row-slice column sums (bf16-rounded) -------
__global__ __launch_bounds__(256) void colsum_kernel(
    const unsigned short* __restrict__ embb, float* __restrict__ colpart) {
  const int d = threadIdx.x;
  const int r0 = blockIdx.x * 256;
  float s = 0.0f;
  for (int i = 0; i < 256; ++i) s += b2f(embb[(size_t)(r0 + i) * DIMD + d]);
  colpart[blockIdx.x * DIMD + d] = s;
}

// ---------- Kernel S2: per-row tau = mu + z*sigma (inline colmean) --------
__global__ __launch_bounds__(256) void tau_kernel(
    const unsigned short* __restrict__ embb, const float* __restrict__ colpart,
    float* __restrict__ tau, float2* __restrict__ musig,
    unsigned* __restrict__ cnts, unsigned* __restrict__ flags) {
  __shared__ float cm[DIMD];
  const int lane = threadIdx.x & 63;
  const int widx = threadIdx.x >> 6;
  const bool bism = blockIdx.x >= 32;
  {
    const int b0 = bism ? 32 : 0, b1 = bism ? 96 : 32;
    const float Ninv = 1.0f / (bism ? (float)NMIR : (float)NDIS);
    float s = 0.0f;
    for (int b = b0; b < b1; ++b) s += colpart[b * DIMD + threadIdx.x];
    cm[threadIdx.x] = s * Ninv;
  }
  __syncthreads();
  const int r0 = blockIdx.x * 256 + widx * 64;
  const float z = bism ? ZM : ZD;
  for (int rr = 0; rr < 64; ++rr) {
    const int row = r0 + rr;
    const float4 cmv = ((const float4*)cm)[lane];
    const ushort4 u = ((const ushort4*)(embb + (size_t)row * DIMD))[lane];
    const float fx = b2f(u.x), fy = b2f(u.y), fz = b2f(u.z), fw = b2f(u.w);
    float dot = fx * cmv.x + fy * cmv.y + fz * cmv.z + fw * cmv.w;
    float nsq = fx * fx + fy * fy + fz * fz + fw * fw;
    dot = wredsum(dot);
    nsq = wredsum(nsq);
    const float sig = sqrtf(nsq);
    if (lane == 0) {
      tau[row] = dot + z * sig;
      musig[row] = make_float2(dot, sig);
      flags[row] = 0u;
    }
    if (lane < 4) cnts[row * 4 + lane] = 0u;
  }
}

// ---------- Kernel B: MFMA sim-GEMM + tau-gated keys + fused pair tail ----
// Grid 768 = exactly 3 blocks/CU. bid<512: mirna (rt=bid>>2, strip=bid&3,
// SW=4096); else disease (SW=2048). Triple-buffered LDS (3x16KB), raw
// s_barrier + counted vmcnt(4). LDS read addresses via precomputed per-lane
// bases vE/vO (XOR swizzle decomposed: addr = base +- s*64 + kk*64, so all
// kk offsets are compile-time immediates).
// (256,3) is the register wall: hipcc splits the unified pool ~50/50
// arch/AGPR with MFMA (arch caps 84/64/48/40 measured at 3/4/5/6 waves).
__global__ __launch_bounds__(256, 3) void knn_kernel(
    const unsigned short* __restrict__ embb, const float* __restrict__ tau,
    unsigned* __restrict__ part, unsigned* __restrict__ cnts,
    unsigned* __restrict__ flags, const float* __restrict__ h,
    const float* __restrict__ srci, const float* __restrict__ dsti,
    const int* __restrict__ dis, const int* __restrict__ mir,
    float* __restrict__ scores, float* __restrict__ pairpart) {
  __shared__ char lds[3 * CBC * 512];  // 3 x 16KB B chunks
  __shared__ float wsum[4];

  const int tid = threadIdx.x;
  const int lane = tid & 63;
  const int widx = tid >> 6;
  const int q4 = lane >> 4;
  const int l15 = lane & 15;
  const int sh16 = q4 * 16;
  const unsigned lmask = (1u << l15) - 1u;

  const int bid = blockIdx.x;
  const bool ism = bid < 512;
  const int rt = ism ? (bid >> 2) : ((bid - 512) >> 2);
  const int strip = ism ? (bid & 3) : ((bid - 512) & 3);
  const int sw = ism ? 4096 : 2048;
  const int nch = sw / CBC;
  const int gbase = ism ? NDIS : 0;
  const unsigned short* fb = embb + (size_t)gbase * DIMD;

  const int rowbase = rt * 128 + widx * 32;  // group-local first row of wave
  const int colstart = strip * sw;
  const char* gb = (const char*)fb;

  // A fragments for 2 row groups (16 rows each)
  bf16x8 afr[2][8];
#pragma unroll
  for (int rg = 0; rg < 2; ++rg) {
    const int arow = rowbase + rg * 16 + l15;
    const char* ab = (const char*)fb + (size_t)arow * 512 + q4 * 16;
#pragma unroll
    for (int kk = 0; kk < 8; ++kk)
      afr[rg][kk] = *(const bf16x8*)(ab + (size_t)kk * 64);
  }

  // LDS read bases: swizzle addr = col*512 + ((kk*64 + q4*16) ^ xr) with
  // xr = (l15&7)<<4 decomposes to base +- s*64 + kk*64 (s = bit2 of l15).
  const int s6 = ((l15 >> 2) & 1) * 64;
  const int Lc = (q4 * 16) ^ ((l15 & 3) << 4);
  int vE[2], vO[2];
#pragma unroll
  for (int t = 0; t < 2; ++t) {
    const int base = t * 8192 + l15 * 512 + Lc;
    vE[t] = base + s6;
    vO[t] = base - s6;
  }

  float tau8[2][4];
  unsigned offb[2];
  int cnt8[2][4];
#pragma unroll
  for (int rg = 0; rg < 2; ++rg) {
    const int db = rowbase + rg * 16 + q4 * 4;
    offb[rg] = (unsigned)(gbase + db) * PSTR + strip * CAP;
#pragma unroll
    for (int j = 0; j < 4; ++j) {
      tau8[rg][j] = tau[gbase + db + j];
      cnt8[rg][j] = 0;
    }
  }

  // B chunk staging: linear LDS dest, inverse-swizzled global source
  auto stage = [&](int dstOff, int cb0n) {
#pragma unroll
    for (int it = 0; it < 4; ++it) {
      const int m = widx * 4 + it;
      const int col = m * 2 + (lane >> 5);
      const int qq = (lane & 31) * 16;
      const int koff = qq ^ ((col & 7) << 4);
      const char* src = gb + (size_t)(colstart + cb0n + col) * 512 + koff;
      __builtin_amdgcn_global_load_lds(
          (const __attribute__((address_space(1))) void*)src,
          (__attribute__((address_space(3))) void*)(lds + dstOff + m * 1024),
          16, 0, 0);
    }
  };

  int o0 = 0, o1 = 16384, o2 = 32768;
  stage(o0, 0);
  stage(o1, CBC);
  for (int ch = 0; ch < nch; ++ch) {
    // counted drain: chunk ch's 4 DMAs complete; ch+1's stay in flight.
    if (ch < nch - 1)
      asm volatile("s_waitcnt vmcnt(4)" ::: "memory");
    else
      asm volatile("s_waitcnt vmcnt(0)" ::: "memory");
    __builtin_amdgcn_sched_barrier(0);
    __builtin_amdgcn_s_barrier();
    __builtin_amdgcn_sched_barrier(0);
    if (ch + 2 < nch) stage(o2, (ch + 2) * CBC);

    const int cb0 = ch * CBC;
    f32x4 acc[2][2];
#pragma unroll
    for (int rg = 0; rg < 2; ++rg)
#pragma unroll
      for (int t = 0; t < 2; ++t) acc[rg][t] = (f32x4){0.f, 0.f, 0.f, 0.f};

#pragma unroll
    for (int t = 0; t < 2; ++t) {
      const char* pE = lds + o0 + vE[t];
      const char* pO = lds + o0 + vO[t];
#pragma unroll
      for (int kp = 0; kp < 4; ++kp) {
        const bf16x8 be = *(const bf16x8*)(pE + kp * 128);
        acc[0][t] = __builtin_amdgcn_mfma_f32_16x16x32_bf16(afr[0][2 * kp], be,
                                                            acc[0][t], 0, 0, 0);
        acc[1][t] = __builtin_amdgcn_mfma_f32_16x16x32_bf16(afr[1][2 * kp], be,
                                                            acc[1][t], 0, 0, 0);
        const bf16x8 bo = *(const bf16x8*)(pO + 64 + kp * 128);
        acc[0][t] = __builtin_amdgcn_mfma_f32_16x16x32_bf16(
            afr[0][2 * kp + 1], bo, acc[0][t], 0, 0, 0);
        acc[1][t] = __builtin_amdgcn_mfma_f32_16x16x32_bf16(
            afr[1][2 * kp + 1], bo, acc[1][t], 0, 0, 0);
      }
    }

    // selection (this buffer's next overwrite is 2 barriers away)
#pragma unroll
    for (int t = 0; t < 2; ++t) {
      const int colb = colstart + cb0 + t * 16;
      const unsigned kc = (unsigned)(16383 - (colb + l15));  // rev-idx tiebrk
#pragma unroll
      for (int rg = 0; rg < 2; ++rg) {
        const bool dchr = (colb == rowbase + rg * 16);  // scalar, rare
#pragma unroll
        for (int j = 0; j < 4; ++j) {
          const float v = acc[rg][t][j];
          bool ok = v > tau8[rg][j];
          if (dchr) ok = ok && (l15 != (q4 * 4 + j));  // skip diagonal
          const ull m = __ballot(ok);
          if (m) {  // wave-uniform early-out
            const unsigned m16 = (unsigned)(m >> sh16) & 0xFFFFu;
            const int rank = __popc(m16 & lmask);
            const int slot = cnt8[rg][j] + rank;
            if (ok && slot < CAP)
              part[offb[rg] + (unsigned)(j * PSTR) + slot] =
                  ((ordu(v) >> 14) << 14) | kc;
            cnt8[rg][j] += __popc(m16);
          }
        }
      }
    }

    const int tp = o0; o0 = o1; o1 = o2; o2 = tp;  // rotate buffers
  }

#pragma unroll
  for (int rg = 0; rg < 2; ++rg) {
#pragma unroll
    for (int j = 0; j < 4; ++j) {
      if (l15 == 0) {
        const int growg = gbase + rowbase + rg * 16 + q4 * 4 + j;
        const int c = cnt8[rg][j];
        cnts[growg * 4 + strip] = (unsigned)(c < CAP ? c : CAP);
        if (c > CAP) flags[growg] = 1u;  // overflow -> exact fallback
      }
    }
  }

  // ---- fused pair phase: this block's slice of the contrastive work ----
  const int gw = bid * 4 + widx;  // 3072 waves
  float lsum = 0.0f;
  for (int b = gw; b < BPAIR; b += NKB * 4) {
    const int d = dis[b];
    const int m = mir[b];
    const float4 a4 = ((const float4*)(h + (size_t)d * DIMD))[lane];
    const float4 m4 = ((const float4*)(h + (size_t)m * DIMD))[lane];
    const float4 s4 = ((const float4*)(srci + (size_t)b * DIMD))[lane];
    const float4 t4 = ((const float4*)(dsti + (size_t)b * DIMD))[lane];
    float aa = dot4f(a4, a4);
    float ss = dot4f(s4, s4);
    float tt = dot4f(t4, t4);
    float as = dot4f(a4, s4);
    float at = dot4f(a4, t4);
    float am = dot4f(a4, m4);
    aa = wredsum(aa); ss = wredsum(ss); tt = wredsum(tt);
    as = wredsum(as); at = wredsum(at); am = wredsum(am);
    const float ra = fmaxf(sqrtf(aa), EPSF);
    const float pos = as / (ra * fmaxf(sqrtf(ss), EPSF));
    const float neg = at / (ra * fmaxf(sqrtf(tt), EPSF));
    lsum += softplusf(neg - pos);
    if (lane == 0) scores[b] = 1.0f / (1.0f + expf(-am));
  }
  if (lane == 0) wsum[widx] = lsum;
  __syncthreads();
  if (tid == 0)
    pairpart[bid] = (wsum[0] + wsum[1]) + (wsum[2] + wsum[3]);
}

// ---------- Kernel F: exact fallback for flagged / under-full rows ----------
__global__ __launch_bounds__(256) void fallback_kernel(
    const unsigned short* __restrict__ embb, const float2* __restrict__ musig,
    unsigned* __restrict__ part, unsigned* __restrict__ cnts,
    const unsigned* __restrict__ flags, unsigned* __restrict__ fbbuf) {
  __shared__ unsigned short frow[4][DIMD];
  const int lane = threadIdx.x & 63;
  const int widx = threadIdx.x >> 6;
  const int wid = blockIdx.x * 4 + widx;
  const ull bel = (1ull << lane) - 1ull;

  for (int row = wid * 96; row < wid * 96 + 96; ++row) {
    unsigned tot = 0;
    for (int s = 0; s < 4; ++s) tot += cnts[row * 4 + s];
    if (!(flags[row] || tot < KSEL)) continue;

    const bool ism = row >= NDIS;
    const int lrow = ism ? row - NDIS : row;
    const int Ng = ism ? NMIR : NDIS;
    const unsigned short* fb = embb + (ism ? (size_t)NDIS * DIMD : 0);
    const float2 ms = musig[row];
    const float tp = ms.x + (ism ? ZFM : ZFD) * ms.y;

    ((ushort4*)frow[widx])[lane] =
        ((const ushort4*)(fb + (size_t)lrow * DIMD))[lane];

    unsigned* fk = fbbuf + (size_t)wid * 4096;
    int fc = 0;
    for (int cb = 0; cb < Ng; cb += 64) {
      const int col = cb + lane;
      float s = 0.0f;
      for (int d0 = 0; d0 < DIMD; d0 += 4) {
        const ushort4 uc = *(const ushort4*)(fb + (size_t)col * DIMD + d0);
        const ushort4 ur = *(const ushort4*)(&frow[widx][d0]);
        s += b2f(uc.x) * b2f(ur.x) + b2f(uc.y) * b2f(ur.y) +
             b2f(uc.z) * b2f(ur.z) + b2f(uc.w) * b2f(ur.w);
      }
      const bool a = (s > tp) && (col != lrow);
      const ull m = __ballot(a);
      const int sl = fc + __popcll(m & bel);
      if (a && sl < 4096) fk[sl] = ((ordu(s) >> 14) << 14) | (16383u - col);
      fc += __popcll(m);
    }
    if (fc > 4096) fc = 4096;

    unsigned lo = 0u, hi = 0xFFFFFFFFu;
    for (int it = 0; it < 32; ++it) {
      const unsigned mid = lo + ((hi - lo) >> 1);
      int c = 0;
      for (int i = lane; i < fc; i += 64) c += (fk[i] > mid) ? 1 : 0;
      c = wredsumi(c);
      if (c >= KSEL) lo = mid; else hi = mid;
    }
    int wc = 0;
    for (int base = 0; base < fc; base += 64) {
      const int i = base + lane;
      const bool w = (i < fc) && (fk[i] > lo);
      const ull m = __ballot(w);
      const int pos = wc + __popcll(m & bel);
      if (w) part[(size_t)row * PSTR + pos] = fk[i];
      wc += __popcll(m);
    }
    if (lane < 4) cnts[row * 4 + lane] = (lane == 0) ? KSEL : 0u;
  }
}

// ---------- Kernel B2: merge strips, exact top-50 by key bisect, gather ----
__global__ __launch_bounds__(256) void merge_kernel(
    const unsigned short* __restrict__ embb, const unsigned* __restrict__ part,
    const unsigned* __restrict__ cnts, float* __restrict__ upd_d,
    float* __restrict__ upd_m) {
  __shared__ unsigned kb[4][PSTR];
  const int lane = threadIdx.x & 63;
  const int widx = threadIdx.x >> 6;
  const int row = blockIdx.x * 4 + widx;
  const bool ism = row >= NDIS;
  const int lrow = ism ? row - NDIS : row;
  const unsigned short* fe = embb + (ism ? (size_t)NDIS * DIMD : 0);
  float* upd =
      (ism ? upd_m + (size_t)lrow * DIMD : upd_d + (size_t)lrow * DIMD);
  const ull bel = (1ull << lane) - 1ull;

  int T = 0;
  for (int s = 0; s < 4; ++s) {
    const int c = (int)cnts[row * 4 + s];
    for (int i = lane; i < c; i += 64)
      kb[widx][T + i] = part[(size_t)row * PSTR + s * CAP + i];
    T += c;
  }
  const int nr = (T + 63) >> 6;  // live regs (wave-uniform)
  unsigned k[5];
#pragma unroll
  for (int i = 0; i < 5; ++i) {
    const int idx = i * 64 + lane;
    k[i] = (idx < T) ? kb[widx][idx] : 0u;
  }

  // bisect: largest lo with count(key > lo) >= 50; keys unique -> exact 50
  unsigned lo = 0u, hi = 0xFFFFFFFFu;
  for (int it = 0; it < 32; ++it) {
    const unsigned mid = lo + ((hi - lo) >> 1);
    int c = 0;
#pragma unroll
    for (int i = 0; i < 5; ++i)
      if (i < nr) c += __popcll(__ballot(k[i] > mid));
    if (c >= KSEL) lo = mid; else hi = mid;
  }
  // winners -> column list in LDS
  int wc = 0;
#pragma unroll
  for (int i = 0; i < 5; ++i) {
    if (i < nr) {
      const bool w = k[i] > lo;
      const ull m = __ballot(w);
      const int pos = wc + __popcll(m & bel);
      if (w) kb[widx][pos] = 16383u - (k[i] & 16383u);
      wc += __popcll(m);
    }
  }

  // gather the 50 neighbors (bf16) and average in fp32
  float ax = 0.f, ay = 0.f, az = 0.f, aw = 0.f;
#pragma unroll 10
  for (int t = 0; t < KSEL; ++t) {
    const int col = (int)kb[widx][t];
    const ushort4 u = ((const ushort4*)(fe + (size_t)col * DIMD))[lane];
    ax += b2f(u.x); ay += b2f(u.y); az += b2f(u.z); aw += b2f(u.w);
  }
  const float inv = 1.0f / (float)KSEL;
  float4 o;
  o.x = ax * inv; o.y = ay * inv; o.z = az * inv; o.w = aw * inv;
  ((float4*)upd)[lane] = o;
}

// ---------- Kernel C1: per-128-row partial sums over concatenated upd ----
__global__ __launch_bounds__(256) void center_partial(
    const float* __restrict__ upd, float* __restrict__ part) {
  const int c = threadIdx.x;
  const int r0 = blockIdx.x * 128;
  float s = 0.0f;
  for (int i = 0; i < 128; ++i) s += upd[(size_t)(r0 + i) * DIMD + c];
  part[blockIdx.x * DIMD + c] = s;
}

// ---------- Kernel C2: finalize both centers + norms (grid 2) ----------
__global__ __launch_bounds__(256) void center_final(
    const float* __restrict__ part, float* __restrict__ center,
    float* __restrict__ cnorm) {
  const int g = blockIdx.x;
  const int c = threadIdx.x;
  const int b0 = g ? 64 : 0, b1 = g ? 192 : 64;
  const float N = g ? (float)NMIR : (float)NDIS;
  float s = 0.0f;
  for (int b = b0; b < b1; ++b) s += part[b * DIMD + c];
  s /= N;
  center[g * DIMD + c] = s;
  __shared__ float red[256];
  red[c] = s * s;
  __syncthreads();
  for (int off = 128; off > 0; off >>= 1) {
    if (c < off) red[c] += red[c + off];
    __syncthreads();
  }
  if (c == 0) cnorm[g] = sqrtf(red[0]);
}

// ---------- Kernel D: both groups' cos-vs-centers softplus partials ------
__global__ __launch_bounds__(256) void knn_loss(
    const float* __restrict__ upd_d, const float* __restrict__ upd_m,
    const float* __restrict__ centers, const float* __restrict__ cnorms,
    float* __restrict__ lpa, float* __restrict__ lpb) {
  const int lane = threadIdx.x & 63;
  const int widx = threadIdx.x >> 6;
  const int bid = blockIdx.x;
  const bool ism = bid >= 128;
  const int lb = ism ? bid - 128 : bid;
  const int N = ism ? NMIR : NDIS;
  const int nw = ism ? 1024 : 512;
  const float* upd = ism ? upd_m : upd_d;
  const int gw = lb * 4 + widx;
  const float4 ca = ((const float4*)centers)[lane];
  const float4 cbv = ((const float4*)(centers + DIMD))[lane];
  const float na = fmaxf(cnorms[0], EPSF);
  const float nb = fmaxf(cnorms[1], EPSF);
  float lsum = 0.0f;
  for (int r = gw; r < N; r += nw) {
    const float4 u = ((const float4*)(upd + (size_t)r * DIMD))[lane];
    float uu = dot4f(u, u);
    float uca = dot4f(u, ca);
    float ucb = dot4f(u, cbv);
    uu = wredsum(uu); uca = wredsum(uca); ucb = wredsum(ucb);
    const float nu = fmaxf(sqrtf(uu), EPSF);
    const float sa = uca / (nu * na);
    const float sb = ucb / (nu * nb);
    const float x = ism ? (sa - sb) : (sb - sa);
    lsum += softplusf(x);
  }
  __shared__ float wsum[4];
  if (lane == 0) wsum[widx] = lsum;
  __syncthreads();
  if (threadIdx.x == 0) {
    const float v = (wsum[0] + wsum[1]) + (wsum[2] + wsum[3]);
    if (ism) lpb[lb] = v; else lpa[lb] = v;
  }
}

// ---------- Kernel E: final scalar reductions ----------
__global__ __launch_bounds__(256) void finalize_kernel(
    const float* __restrict__ pairpart, const float* __restrict__ lpa,
    const float* __restrict__ lpb, float* __restrict__ out) {
  __shared__ float red[256];
  const int t = threadIdx.x;

  float s = 0.0f;
  for (int i = t; i < NKB; i += 256) s += pairpart[i];
  red[t] = s;
  __syncthreads();
  for (int off = 128; off > 0; off >>= 1) {
    if (t < off) red[t] += red[t + off];
    __syncthreads();
  }
  const float pairsum = red[0];
  __syncthreads();

  red[t] = (t < 128) ? lpa[t] : 0.0f;
  __syncthreads();
  for (int off = 128; off > 0; off >>= 1) {
    if (t < off) red[t] += red[t + off];
    __syncthreads();
  }
  const float la = red[0];
  __syncthreads();

  red[t] = lpb[t];
  __syncthreads();
  for (int off = 128; off > 0; off >>= 1) {
    if (t < off) red[t] += red[t + off];
    __syncthreads();
  }
  const float lb = red[0];

  if (t == 0) {
    out[BPAIR] = pairsum / (float)BPAIR;
    out[BPAIR + 1] = 0.5f * (la / (float)NDIS + lb / (float)NMIR);
  }
}

extern "C" void kernel_launch(void* const* d_in, const int* in_sizes, int n_in,
                              void* d_out, int out_size, void* d_ws,
                              size_t ws_size, hipStream_t stream) {
  const float* h = (const float*)d_in[0];
  const float* emb = (const float*)d_in[1];
  const float* srci = (const float*)d_in[2];
  const float* dsti = (const float*)d_in[3];
  const int* dis = (const int*)d_in[4];
  const int* mir = (const int*)d_in[5];
  float* out = (float*)d_out;

  float* W = (float*)d_ws;
  float* upd_d = W;                                    // 8192*256 f32
  float* upd_m = upd_d + (size_t)NDIS * DIMD;          // 16384*256 f32
  float* pairpart = upd_m + (size_t)NMIR * DIMD;       // 768 (pad 1024)
  float* cpart = pairpart + 1024;                      // 192*256
  float* centers = cpart + 192 * DIMD;                 // 512
  float* cnorms = centers + 512;                       // 2 (pad 64)
  float* lpa = cnorms + 64;                            // 128
  float* lpb = lpa + 128;                              // 256
  float* colpart = lpb + 256;                          // 96*256
  float* tau = colpart + 96 * DIMD;                    // 24576
  float2* musig = (float2*)(tau + NTOT);               // 24576 float2
  unsigned* flags = (unsigned*)(musig + NTOT);         // 24576 u32
  unsigned* cnts = flags + NTOT;                       // 24576*4 u32
  unsigned short* embb = (unsigned short*)(cnts + NTOT * 4);  // 24576*256 bf16
  unsigned* part = (unsigned*)(embb + (size_t)NTOT * DIMD);   // 24576*320 u32
  unsigned* fbbuf = part + (size_t)NTOT * PSTR;        // 256*4096 u32

  convert_kernel<<<(NTOT * DIMD) / 1024, 256, 0, stream>>>(emb, embb);
  colsum_kernel<<<96, 256, 0, stream>>>(embb, colpart);
  tau_kernel<<<96, 256, 0, stream>>>(embb, colpart, tau, musig, cnts, flags);
  knn_kernel<<<NKB, 256, 0, stream>>>(embb, tau, part, cnts, flags, h, srci,
                                      dsti, dis, mir, out, pairpart);
  fallback_kernel<<<64, 256, 0, stream>>>(embb, musig, part, cnts, flags,
                                          fbbuf);
  merge_kernel<<<NTOT / 4, 256, 0, stream>>>(embb, part, cnts, upd_d, upd_m);
  center_partial<<<192, 256, 0, stream>>>(upd_d, cpart);
  center_final<<<2, 256, 0, stream>>>(cpart, centers, cnorms);
  knn_loss<<<384, 256, 0, stream>>>(upd_d, upd_m, centers, cnorms, lpa, lpb);
  finalize_kernel<<<1, 256, 0, stream>>>(pairpart, lpa, lpb, out);
}